// Round 1
// baseline (157.681 us; speedup 1.0000x reference)
//
#include <hip/hip_runtime.h>
#include <math.h>

#define B_SZ 256
#define N_SZ 1024
#define D_MODEL 128
#define NUM_CLASSES 32
#define ETA 4.0f
#define RC_F 6.0f
#define NR 4

// sh/radial/env product for one point. Returns r and class; fills p[4].
__device__ __forceinline__ void compute_prod(const float4 xv, float& r, int& c, float p[4]) {
    const float y00 = 0.28209479177387814f;  // 0.5/sqrt(pi)
    const float c1  = 0.48860251190291992f;  // sqrt(3/(4pi))
    const float PI_F = 3.14159265358979323846f;
    float r2 = xv.x * xv.x + xv.y * xv.y + xv.z * xv.z;
    r = sqrtf(r2);
    c = (int)xv.w;
    float inv_r = (r > 0.0f) ? (1.0f / r) : 0.0f;  // u = 0 when r==0 (xyz all zero)
    float ux = xv.x * inv_r, uy = xv.y * inv_r, uz = xv.z * inv_r;
    float rc = fminf(r, RC_F);
    float env = 0.5f * cosf((PI_F / RC_F) * rc) + 0.5f;
    float d0 = 0.0f - r, d1 = 1.5f - r, d2 = 3.0f - r, d3 = 4.5f - r;
    float rad0 = expf(-ETA * d0 * d0);
    float rad1 = expf(-ETA * d1 * d1);
    float rad2 = expf(-ETA * d2 * d2);
    float rad3 = expf(-ETA * d3 * d3);
    p[0] = y00 * rad0 * env;
    p[1] = c1 * uy * rad1 * env;
    p[2] = c1 * uz * rad2 * env;
    p[3] = c1 * ux * rad3 * env;
}

// Kernel A: one block per batch. Accumulate sum of prod^2 per feature in LDS,
// then write inv_norm = 1/max(sqrt(nsq), 1e-12) to ws (B*128 floats).
__global__ __launch_bounds__(256) void ape_norm_kernel(const float* __restrict__ x,
                                                       float* __restrict__ inv_norm) {
    __shared__ float nsq[D_MODEL];
    const int b = blockIdx.x;
    const int t = threadIdx.x;
    if (t < D_MODEL) nsq[t] = 0.0f;
    __syncthreads();
    const float4* xb = (const float4*)(x + (size_t)b * N_SZ * 4);
    for (int n = t; n < N_SZ; n += 256) {
        float4 xv = xb[n];
        float r; int c; float p[4];
        compute_prod(xv, r, c, p);
        if (r > 0.0f) {
            atomicAdd(&nsq[0 * NUM_CLASSES + c], p[0] * p[0]);
            atomicAdd(&nsq[1 * NUM_CLASSES + c], p[1] * p[1]);
            atomicAdd(&nsq[2 * NUM_CLASSES + c], p[2] * p[2]);
            atomicAdd(&nsq[3 * NUM_CLASSES + c], p[3] * p[3]);
        }
    }
    __syncthreads();
    if (t < D_MODEL) {
        float nv = sqrtf(nsq[t]);
        inv_norm[b * D_MODEL + t] = 1.0f / fmaxf(nv, 1e-12f);
    }
}

// Kernel B: 32 lanes per point. Each lane writes one float4 (features 4*lane..4*lane+3).
__global__ __launch_bounds__(256) void ape_main_kernel(const float* __restrict__ x,
                                                       const float* __restrict__ inv_norm,
                                                       float* __restrict__ out) {
    const int gid = blockIdx.x * 256 + threadIdx.x;
    const int pt = gid >> 5;    // point index in [0, B*N)
    const int lane = gid & 31;  // feature group
    const int b = pt >> 10;     // N = 1024

    const float4 xv = ((const float4*)x)[pt];
    float r; int c; float p[4];
    compute_prod(xv, r, c, p);

    float4 o = make_float4(0.0f, 0.0f, 0.0f, 0.0f);
    if (r > 0.0f) {
        const float* nb = inv_norm + b * D_MODEL + c;
        float pn0 = p[0] * nb[0];
        float pn1 = p[1] * nb[32];
        float pn2 = p[2] * nb[64];
        float pn3 = p[3] * nb[96];
        float sum = pn0 + pn1 + pn2 + pn3;
        float mean = sum * (1.0f / 128.0f);
        float sumsq = pn0 * pn0 + pn1 * pn1 + pn2 * pn2 + pn3 * pn3;
        float var = (sumsq - 128.0f * mean * mean) * (1.0f / 127.0f);
        var = fmaxf(var, 0.0f);
        float inv_std = 1.0f / (sqrtf(var) + 1e-6f);
        // This lane's radial index and class range
        float pni = (lane < 8) ? pn0 : (lane < 16) ? pn1 : (lane < 24) ? pn2 : pn3;
        const int cc0 = (lane & 7) * 4;
        o.x = (((cc0 + 0) == c ? pni : 0.0f) - mean) * inv_std;
        o.y = (((cc0 + 1) == c ? pni : 0.0f) - mean) * inv_std;
        o.z = (((cc0 + 2) == c ? pni : 0.0f) - mean) * inv_std;
        o.w = (((cc0 + 3) == c ? pni : 0.0f) - mean) * inv_std;
    }
    ((float4*)out)[(size_t)pt * 32 + lane] = o;
}

extern "C" void kernel_launch(void* const* d_in, const int* in_sizes, int n_in,
                              void* d_out, int out_size, void* d_ws, size_t ws_size,
                              hipStream_t stream) {
    const float* x = (const float*)d_in[0];
    float* out = (float*)d_out;
    float* inv_norm = (float*)d_ws;  // B * D_MODEL floats = 128 KiB

    ape_norm_kernel<<<B_SZ, 256, 0, stream>>>(x, inv_norm);

    // B*N points, 32 lanes each, 256 threads/block -> B*N*32/256 blocks
    const int total_threads = B_SZ * N_SZ * 32;
    ape_main_kernel<<<total_threads / 256, 256, 0, stream>>>(x, inv_norm, out);
}

// Round 2
// 146.655 us; speedup vs baseline: 1.0752x; 1.0752x over previous
//
#include <hip/hip_runtime.h>
#include <math.h>

#define B_SZ 256
#define N_SZ 1024
#define D_MODEL 128
#define NUM_CLASSES 32
#define NR 4

// exp(-ETA*d^2) = 2^(d^2 * -ETA*log2(e));  -4 * 1.4426950408889634
#define K_EXP (-5.770780163555854f)
// cos(pi*rc/RC) with v_cos (revolutions): cos(2*pi * rc/(2*RC)) -> arg = rc/12
#define K_COS (1.0f / 12.0f)

// sh/radial/env product for one point using single-instruction HW transcendentals.
__device__ __forceinline__ void compute_prod(const float4 xv, float& r, int& c, float p[4]) {
    const float y00 = 0.28209479177387814f;  // 0.5/sqrt(pi)
    const float c1  = 0.48860251190291992f;  // sqrt(3/(4pi))
    float r2 = xv.x * xv.x + xv.y * xv.y + xv.z * xv.z;
    r = sqrtf(r2);                            // v_sqrt_f32
    c = (int)xv.w;
    float inv_r = (r > 0.0f) ? __builtin_amdgcn_rcpf(r) : 0.0f;  // v_rcp_f32
    float ux = xv.x * inv_r, uy = xv.y * inv_r, uz = xv.z * inv_r;
    float rc = fminf(r, 6.0f);
    float env = 0.5f * __builtin_amdgcn_cosf(rc * K_COS) + 0.5f;  // v_cos_f32 (revolutions)
    float d0 = 0.0f - r, d1 = 1.5f - r, d2 = 3.0f - r, d3 = 4.5f - r;
    float rad0 = __builtin_amdgcn_exp2f(d0 * d0 * K_EXP);
    float rad1 = __builtin_amdgcn_exp2f(d1 * d1 * K_EXP);
    float rad2 = __builtin_amdgcn_exp2f(d2 * d2 * K_EXP);
    float rad3 = __builtin_amdgcn_exp2f(d3 * d3 * K_EXP);
    p[0] = y00 * rad0 * env;
    p[1] = c1 * uy * rad1 * env;
    p[2] = c1 * uz * rad2 * env;
    p[3] = c1 * ux * rad3 * env;
}

// Kernel A: one block per batch. Accumulate sum of prod^2 per feature in LDS,
// then write inv_norm = 1/max(sqrt(nsq), 1e-12) to ws (B*128 floats).
__global__ __launch_bounds__(256) void ape_norm_kernel(const float* __restrict__ x,
                                                       float* __restrict__ inv_norm) {
    __shared__ float nsq[D_MODEL];
    const int b = blockIdx.x;
    const int t = threadIdx.x;
    if (t < D_MODEL) nsq[t] = 0.0f;
    __syncthreads();
    const float4* xb = (const float4*)(x + (size_t)b * N_SZ * 4);
    for (int n = t; n < N_SZ; n += 256) {
        float4 xv = xb[n];
        float r; int c; float p[4];
        compute_prod(xv, r, c, p);
        if (r > 0.0f) {
            atomicAdd(&nsq[0 * NUM_CLASSES + c], p[0] * p[0]);
            atomicAdd(&nsq[1 * NUM_CLASSES + c], p[1] * p[1]);
            atomicAdd(&nsq[2 * NUM_CLASSES + c], p[2] * p[2]);
            atomicAdd(&nsq[3 * NUM_CLASSES + c], p[3] * p[3]);
        }
    }
    __syncthreads();
    if (t < D_MODEL) {
        float nv = sqrtf(nsq[t]);
        inv_norm[b * D_MODEL + t] = __builtin_amdgcn_rcpf(fmaxf(nv, 1e-12f));
    }
}

// Kernel B: 32 lanes per point. Each lane writes one float4 (features 4*lane..4*lane+3).
__global__ __launch_bounds__(256) void ape_main_kernel(const float* __restrict__ x,
                                                       const float* __restrict__ inv_norm,
                                                       float* __restrict__ out) {
    const int gid = blockIdx.x * 256 + threadIdx.x;
    const int pt = gid >> 5;    // point index in [0, B*N)
    const int lane = gid & 31;  // feature group
    const int b = pt >> 10;     // N = 1024

    const float4 xv = ((const float4*)x)[pt];
    float r; int c; float p[4];
    compute_prod(xv, r, c, p);

    float4 o = make_float4(0.0f, 0.0f, 0.0f, 0.0f);
    if (r > 0.0f) {
        const float* nb = inv_norm + b * D_MODEL + c;
        float pn0 = p[0] * nb[0];
        float pn1 = p[1] * nb[32];
        float pn2 = p[2] * nb[64];
        float pn3 = p[3] * nb[96];
        float sum = pn0 + pn1 + pn2 + pn3;
        float mean = sum * (1.0f / 128.0f);
        float sumsq = pn0 * pn0 + pn1 * pn1 + pn2 * pn2 + pn3 * pn3;
        float var = (sumsq - 128.0f * mean * mean) * (1.0f / 127.0f);
        var = fmaxf(var, 0.0f);
        float inv_std = __builtin_amdgcn_rcpf(sqrtf(var) + 1e-6f);
        // (pni - mean)*inv_std if feature matches, else (0 - mean)*inv_std
        float pni = (lane < 8) ? pn0 : (lane < 16) ? pn1 : (lane < 24) ? pn2 : pn3;
        float bneg = -mean * inv_std;
        float amb = pni * inv_std + bneg;
        const int cc0 = (lane & 7) * 4;
        o.x = ((cc0 + 0) == c) ? amb : bneg;
        o.y = ((cc0 + 1) == c) ? amb : bneg;
        o.z = ((cc0 + 2) == c) ? amb : bneg;
        o.w = ((cc0 + 3) == c) ? amb : bneg;
    }
    ((float4*)out)[(size_t)pt * 32 + lane] = o;
}

extern "C" void kernel_launch(void* const* d_in, const int* in_sizes, int n_in,
                              void* d_out, int out_size, void* d_ws, size_t ws_size,
                              hipStream_t stream) {
    const float* x = (const float*)d_in[0];
    float* out = (float*)d_out;
    float* inv_norm = (float*)d_ws;  // B * D_MODEL floats = 128 KiB

    ape_norm_kernel<<<B_SZ, 256, 0, stream>>>(x, inv_norm);

    const int total_threads = B_SZ * N_SZ * 32;
    ape_main_kernel<<<total_threads / 256, 256, 0, stream>>>(x, inv_norm, out);
}

// Round 3
// 140.149 us; speedup vs baseline: 1.1251x; 1.0464x over previous
//
#include <hip/hip_runtime.h>
#include <math.h>

#define B_SZ 256
#define N_SZ 1024
#define D_MODEL 128
#define NUM_CLASSES 32
#define NR 4

// exp(-ETA*d^2) = 2^(d^2 * -ETA*log2(e));  -4 * 1.4426950408889634
#define K_EXP (-5.770780163555854f)
// cos(pi*rc/RC) with v_cos (revolutions): cos(2*pi * rc/(2*RC)) -> arg = rc/12
#define K_COS (1.0f / 12.0f)

// sh/radial/env product for one point using single-instruction HW transcendentals.
__device__ __forceinline__ void compute_prod(const float4 xv, float& r, int& c, float p[4]) {
    const float y00 = 0.28209479177387814f;  // 0.5/sqrt(pi)
    const float c1  = 0.48860251190291992f;  // sqrt(3/(4pi))
    float r2 = xv.x * xv.x + xv.y * xv.y + xv.z * xv.z;
    r = sqrtf(r2);                            // v_sqrt_f32
    c = (int)xv.w;
    float inv_r = (r > 0.0f) ? __builtin_amdgcn_rcpf(r) : 0.0f;  // v_rcp_f32
    float ux = xv.x * inv_r, uy = xv.y * inv_r, uz = xv.z * inv_r;
    float rc = fminf(r, 6.0f);
    float env = 0.5f * __builtin_amdgcn_cosf(rc * K_COS) + 0.5f;  // v_cos_f32 (revolutions)
    float d0 = 0.0f - r, d1 = 1.5f - r, d2 = 3.0f - r, d3 = 4.5f - r;
    float rad0 = __builtin_amdgcn_exp2f(d0 * d0 * K_EXP);
    float rad1 = __builtin_amdgcn_exp2f(d1 * d1 * K_EXP);
    float rad2 = __builtin_amdgcn_exp2f(d2 * d2 * K_EXP);
    float rad3 = __builtin_amdgcn_exp2f(d3 * d3 * K_EXP);
    p[0] = y00 * rad0 * env;
    p[1] = c1 * uy * rad1 * env;
    p[2] = c1 * uz * rad2 * env;
    p[3] = c1 * ux * rad3 * env;
}

// Kernel A: one block (1024 threads) per batch, one point per thread.
// Accumulate sum of prod^2 per feature in LDS, write inv_norm to ws.
__global__ __launch_bounds__(1024) void ape_norm_kernel(const float* __restrict__ x,
                                                        float* __restrict__ inv_norm) {
    __shared__ float nsq[D_MODEL];
    const int b = blockIdx.x;
    const int t = threadIdx.x;
    if (t < D_MODEL) nsq[t] = 0.0f;
    __syncthreads();
    float4 xv = ((const float4*)x)[(size_t)b * N_SZ + t];
    float r; int c; float p[4];
    compute_prod(xv, r, c, p);
    if (r > 0.0f) {
        atomicAdd(&nsq[0 * NUM_CLASSES + c], p[0] * p[0]);
        atomicAdd(&nsq[1 * NUM_CLASSES + c], p[1] * p[1]);
        atomicAdd(&nsq[2 * NUM_CLASSES + c], p[2] * p[2]);
        atomicAdd(&nsq[3 * NUM_CLASSES + c], p[3] * p[3]);
    }
    __syncthreads();
    if (t < D_MODEL) {
        float nv = sqrtf(nsq[t]);
        inv_norm[b * D_MODEL + t] = __builtin_amdgcn_rcpf(fmaxf(nv, 1e-12f));
    }
}

// Kernel B: 4 lanes per point. Lane sub writes 8 float4 stores; store j covers
// features [j*16 + sub*4 .. +3] at byte offset pt*512 + j*64 + sub*16, so each
// wave store instruction writes 16 full 64B cachelines.
__global__ __launch_bounds__(256) void ape_main_kernel(const float* __restrict__ x,
                                                       const float* __restrict__ inv_norm,
                                                       float* __restrict__ out) {
    const int gid = blockIdx.x * 256 + threadIdx.x;
    const int pt = gid >> 2;    // point index in [0, B*N)
    const int sub = gid & 3;    // quad lane
    const int b = pt >> 10;     // N = 1024

    const float4 xv = ((const float4*)x)[pt];
    float r; int c; float p[4];
    compute_prod(xv, r, c, p);

    float bneg = 0.0f;
    float amb[4] = {0.0f, 0.0f, 0.0f, 0.0f};
    if (r > 0.0f) {
        const float* nb = inv_norm + b * D_MODEL + c;
        float pn0 = p[0] * nb[0];
        float pn1 = p[1] * nb[32];
        float pn2 = p[2] * nb[64];
        float pn3 = p[3] * nb[96];
        float sum = pn0 + pn1 + pn2 + pn3;
        float mean = sum * (1.0f / 128.0f);
        float sumsq = pn0 * pn0 + pn1 * pn1 + pn2 * pn2 + pn3 * pn3;
        float var = (sumsq - 128.0f * mean * mean) * (1.0f / 127.0f);
        var = fmaxf(var, 0.0f);
        float inv_std = __builtin_amdgcn_rcpf(sqrtf(var) + 1e-6f);
        bneg = -mean * inv_std;
        amb[0] = pn0 * inv_std + bneg;
        amb[1] = pn1 * inv_std + bneg;
        amb[2] = pn2 * inv_std + bneg;
        amb[3] = pn3 * inv_std + bneg;
    }
    float4* ob = (float4*)out + (size_t)pt * 32 + sub;  // + j*4 per store
    const int hb = sub * 4;  // class base within 16-block, plus (j&1)*16
#pragma unroll
    for (int j = 0; j < 8; ++j) {
        const float a = amb[j >> 1];
        const int cb = (j & 1) * 16 + hb;
        float4 o;
        o.x = (cb + 0 == c) ? a : bneg;
        o.y = (cb + 1 == c) ? a : bneg;
        o.z = (cb + 2 == c) ? a : bneg;
        o.w = (cb + 3 == c) ? a : bneg;
        ob[j * 4] = o;
    }
}

extern "C" void kernel_launch(void* const* d_in, const int* in_sizes, int n_in,
                              void* d_out, int out_size, void* d_ws, size_t ws_size,
                              hipStream_t stream) {
    const float* x = (const float*)d_in[0];
    float* out = (float*)d_out;
    float* inv_norm = (float*)d_ws;  // B * D_MODEL floats = 128 KiB

    ape_norm_kernel<<<B_SZ, 1024, 0, stream>>>(x, inv_norm);

    // B*N points, 4 lanes each, 256 threads/block
    const int total_threads = B_SZ * N_SZ * 4;
    ape_main_kernel<<<total_threads / 256, 256, 0, stream>>>(x, inv_norm, out);
}

// Round 4
// 138.552 us; speedup vs baseline: 1.1381x; 1.0115x over previous
//
#include <hip/hip_runtime.h>
#include <math.h>

#define B_SZ 256
#define N_SZ 1024
#define D_MODEL 128
#define NUM_CLASSES 32

// exp(-ETA*d^2) = 2^(d^2 * -ETA*log2(e));  -4 * 1.4426950408889634
#define K_EXP (-5.770780163555854f)
// cos(pi*rc/RC) with v_cos (revolutions): arg = rc/(2*RC) = rc/12
#define K_COS (1.0f / 12.0f)

__device__ __forceinline__ void compute_prod(const float4 xv, float& r, int& c, float p[4]) {
    const float y00 = 0.28209479177387814f;  // 0.5/sqrt(pi)
    const float c1  = 0.48860251190291992f;  // sqrt(3/(4pi))
    float r2 = xv.x * xv.x + xv.y * xv.y + xv.z * xv.z;
    r = sqrtf(r2);
    c = (int)xv.w;
    float inv_r = (r > 0.0f) ? __builtin_amdgcn_rcpf(r) : 0.0f;
    float ux = xv.x * inv_r, uy = xv.y * inv_r, uz = xv.z * inv_r;
    float rc = fminf(r, 6.0f);
    float env = 0.5f * __builtin_amdgcn_cosf(rc * K_COS) + 0.5f;
    float d0 = 0.0f - r, d1 = 1.5f - r, d2 = 3.0f - r, d3 = 4.5f - r;
    float rad0 = __builtin_amdgcn_exp2f(d0 * d0 * K_EXP);
    float rad1 = __builtin_amdgcn_exp2f(d1 * d1 * K_EXP);
    float rad2 = __builtin_amdgcn_exp2f(d2 * d2 * K_EXP);
    float rad3 = __builtin_amdgcn_exp2f(d3 * d3 * K_EXP);
    p[0] = y00 * rad0 * env;
    p[1] = c1 * uy * rad1 * env;
    p[2] = c1 * uz * rad2 * env;
    p[3] = c1 * ux * rad3 * env;
}

// One block per batch (1024 threads = 1024 points). Three phases:
//  1. per-point prod -> LDS SoA; sum of squares per feature via LDS atomics
//  2. inv_norm[128] in LDS
//  3. coalesced output: 4 lanes/point, store j covers features [j*16+sub*4, +4)
//     at byte pt*512 + j*64 + sub*16 -> each wave store = 16 full 64B lines.
__global__ __launch_bounds__(1024) void ape_fused_kernel(const float* __restrict__ x,
                                                         float* __restrict__ out) {
    __shared__ float nsq[D_MODEL];
    __shared__ float invn[D_MODEL];
    __shared__ float sp0[N_SZ], sp1[N_SZ], sp2[N_SZ], sp3[N_SZ];
    __shared__ int   scls[N_SZ];

    const int b = blockIdx.x;
    const int t = threadIdx.x;
    if (t < D_MODEL) nsq[t] = 0.0f;
    __syncthreads();

    // Phase 1: one point per thread
    {
        float4 xv = ((const float4*)x)[(size_t)b * N_SZ + t];
        float r; int c; float p[4];
        compute_prod(xv, r, c, p);
        if (r <= 0.0f) { p[0] = p[1] = p[2] = p[3] = 0.0f; }
        sp0[t] = p[0]; sp1[t] = p[1]; sp2[t] = p[2]; sp3[t] = p[3];
        scls[t] = c;
        if (r > 0.0f) {
            atomicAdd(&nsq[0 * NUM_CLASSES + c], p[0] * p[0]);
            atomicAdd(&nsq[1 * NUM_CLASSES + c], p[1] * p[1]);
            atomicAdd(&nsq[2 * NUM_CLASSES + c], p[2] * p[2]);
            atomicAdd(&nsq[3 * NUM_CLASSES + c], p[3] * p[3]);
        }
    }
    __syncthreads();

    // Phase 2: inv_norm per feature
    if (t < D_MODEL) {
        invn[t] = __builtin_amdgcn_rcpf(fmaxf(sqrtf(nsq[t]), 1e-12f));
    }
    __syncthreads();

    // Phase 3: 4 lanes per point, 4 passes of 256 points
    const int sub = t & 3;
    const int hb = sub * 4;
#pragma unroll
    for (int k = 0; k < 4; ++k) {
        const int n = k * 256 + (t >> 2);
        const int c = scls[n];
        float pn0 = sp0[n] * invn[0 * NUM_CLASSES + c];
        float pn1 = sp1[n] * invn[1 * NUM_CLASSES + c];
        float pn2 = sp2[n] * invn[2 * NUM_CLASSES + c];
        float pn3 = sp3[n] * invn[3 * NUM_CLASSES + c];
        float sum = pn0 + pn1 + pn2 + pn3;
        float mean = sum * (1.0f / 128.0f);
        float sumsq = pn0 * pn0 + pn1 * pn1 + pn2 * pn2 + pn3 * pn3;
        float var = fmaxf((sumsq - 128.0f * mean * mean) * (1.0f / 127.0f), 0.0f);
        float inv_std = __builtin_amdgcn_rcpf(sqrtf(var) + 1e-6f);
        float bneg = -mean * inv_std;
        float amb[4];
        amb[0] = pn0 * inv_std + bneg;
        amb[1] = pn1 * inv_std + bneg;
        amb[2] = pn2 * inv_std + bneg;
        amb[3] = pn3 * inv_std + bneg;

        float4* ob = (float4*)out + ((size_t)b * N_SZ + n) * 32 + sub;
#pragma unroll
        for (int j = 0; j < 8; ++j) {
            const float a = amb[j >> 1];
            const int cb = (j & 1) * 16 + hb;
            float4 o;
            o.x = (cb + 0 == c) ? a : bneg;
            o.y = (cb + 1 == c) ? a : bneg;
            o.z = (cb + 2 == c) ? a : bneg;
            o.w = (cb + 3 == c) ? a : bneg;
            ob[j * 4] = o;
        }
    }
}

extern "C" void kernel_launch(void* const* d_in, const int* in_sizes, int n_in,
                              void* d_out, int out_size, void* d_ws, size_t ws_size,
                              hipStream_t stream) {
    const float* x = (const float*)d_in[0];
    float* out = (float*)d_out;
    ape_fused_kernel<<<B_SZ, 1024, 0, stream>>>(x, out);
}